// Round 4
// baseline (245.172 us; speedup 1.0000x reference)
//
#include <hip/hip_runtime.h>
#include <hip/hip_bf16.h>

#define H      128
#define NB     256
#define NRES   262144
#define CHUNK  128
#define NCHUNK (NRES / CHUNK)   // 2048 chunk blocks
#define QBLK   (NB / 2)         // 128 extra blocks for q (2 rows each)
#define PIECES 128              // piece slots per segment (segment spans <= ~38 windows of 32 rows)
#define REC    136              // floats per piece record: m, s, pad[6], v[128]

typedef __attribute__((ext_vector_type(4))) float f32x4;
typedef __attribute__((ext_vector_type(8))) short short8;

__device__ __forceinline__ short bf16cvt(float f) {
  unsigned u = __builtin_bit_cast(unsigned, f);
  unsigned r = (u + 0x7fffu + ((u >> 16) & 1u)) >> 16;  // RNE
  return (short)r;
}

__device__ __forceinline__ short8 pack_bf16x8(f32x4 x, f32x4 y) {
  short8 v;
  v[0] = bf16cvt(x[0]); v[1] = bf16cvt(x[1]);
  v[2] = bf16cvt(x[2]); v[3] = bf16cvt(x[3]);
  v[4] = bf16cvt(y[0]); v[5] = bf16cvt(y[1]);
  v[6] = bf16cvt(y[2]); v[7] = bf16cvt(y[3]);
  return v;
}

__device__ __forceinline__ int lower_bound_i(const int* __restrict__ a, int n, int v) {
  int lo = 0, hi = n;
  while (lo < hi) { int mid = (lo + hi) >> 1; if (a[mid] < v) lo = mid + 1; else hi = mid; }
  return lo;
}

// ---- kernel 1 (fused): per-128-row chunk flash partials + q rows in tail blocks ----
// chunk blocks: k = relu(prot Wk^T + bk) via MFMA (k stays in registers),
//   score = k . wm1  (q-side term dropped: constant per segment, cancels in softmax),
//   per-32-row-window per-segment piece records (m, sum e, sum e*k).
// Wk frag: f = ct*4+kk ; lane l holds B[k=(l>>4)*8+j][col=(l&15)]
//        = Wk[ct*16+(l&15)][kk*32+(l>>4)*8+j]
__global__ __launch_bounds__(256) void flashkern(
    const float* __restrict__ prot, const int* __restrict__ batch,
    const float* __restrict__ Wk, const float* __restrict__ bk,
    const float* __restrict__ Wm, const float* __restrict__ mol,
    const float* __restrict__ Wq, const float* __restrict__ bq,
    float* __restrict__ out, float* __restrict__ part) {
  int tid = threadIdx.x;

  if (blockIdx.x >= NCHUNK) {
    // ---- q path: q = relu(mol Wq^T + bq), exact f32; 2 rows per block ----
    int b = (blockIdx.x - NCHUNK) * 2 + (tid >> 7);
    int h = tid & 127;
    const float* mrow = mol + b * H;
    const float* wrow = Wq + h * H;
    float acc = bq[h];
#pragma unroll 8
    for (int j = 0; j < H; ++j) acc = fmaf(mrow[j], wrow[j], acc);
    out[NB * H + b * H + h] = fmaxf(acc, 0.f);
    return;
  }

  __shared__ short bfrag[2048 * 8];     // 32 KB packed Wk frags
  __shared__ float score_sh[CHUNK];
  __shared__ int   batch_sh[CHUNK];

  int c0row = blockIdx.x * CHUNK;

  // pack Wk -> bf16 frags in LDS (Wk is L2-resident; 8 slots/thread)
  for (int slot = tid; slot < 2048; slot += 256) {
    int f = slot >> 6, l = slot & 63;
    int ct = f >> 2, kk = f & 3;
    const float* src = Wk + (ct * 16 + (l & 15)) * H + kk * 32 + (l >> 4) * 8;
    f32x4 x = *(const f32x4*)src;
    f32x4 y = *(const f32x4*)(src + 4);
    *(short8*)&bfrag[slot * 8] = pack_bf16x8(x, y);
  }
  if (tid < 32) ((int4*)batch_sh)[tid] = ((const int4*)(batch + c0row))[tid];
  __syncthreads();

  int w = tid >> 6, l = tid & 63;
  int cg = l & 15, kg = l >> 4;
  float wm1v[8], bkv[8];
#pragma unroll
  for (int ct = 0; ct < 8; ++ct) { wm1v[ct] = Wm[ct * 16 + cg]; bkv[ct] = bk[ct * 16 + cg]; }

  // ---- MFMA: this wave's 32 rows as two 16-row tiles; k kept in acc registers ----
  f32x4 acc0[8], acc1[8];
#pragma unroll
  for (int tile = 0; tile < 2; ++tile) {
    f32x4* acc = tile ? acc1 : acc0;
    int rbase = w * 32 + tile * 16;
    const float* pbase = prot + (size_t)(c0row + rbase + cg) * H + kg * 8;
    short8 a[4];
#pragma unroll
    for (int kk = 0; kk < 4; ++kk) {
      f32x4 x = *(const f32x4*)(pbase + kk * 32);
      f32x4 y = *(const f32x4*)(pbase + kk * 32 + 4);
      a[kk] = pack_bf16x8(x, y);
    }
#pragma unroll
    for (int ct = 0; ct < 8; ++ct) acc[ct] = (f32x4){0.f, 0.f, 0.f, 0.f};
#pragma unroll
    for (int ct = 0; ct < 8; ++ct)
#pragma unroll
      for (int kk = 0; kk < 4; ++kk) {
        short8 bf = *(const short8*)&bfrag[((ct * 4 + kk) * 64 + l) * 8];
        acc[ct] = __builtin_amdgcn_mfma_f32_16x16x32_bf16(a[kk], bf, acc[ct], 0, 0, 0);
      }
    // relu+bias in-place (acc becomes k), score dot partials
    float p0 = 0.f, p1 = 0.f, p2 = 0.f, p3 = 0.f;
#pragma unroll
    for (int ct = 0; ct < 8; ++ct) {
      acc[ct][0] = fmaxf(acc[ct][0] + bkv[ct], 0.f);
      acc[ct][1] = fmaxf(acc[ct][1] + bkv[ct], 0.f);
      acc[ct][2] = fmaxf(acc[ct][2] + bkv[ct], 0.f);
      acc[ct][3] = fmaxf(acc[ct][3] + bkv[ct], 0.f);
      p0 += acc[ct][0] * wm1v[ct]; p1 += acc[ct][1] * wm1v[ct];
      p2 += acc[ct][2] * wm1v[ct]; p3 += acc[ct][3] * wm1v[ct];
    }
#pragma unroll
    for (int off = 1; off < 16; off <<= 1) {
      p0 += __shfl_xor(p0, off); p1 += __shfl_xor(p1, off);
      p2 += __shfl_xor(p2, off); p3 += __shfl_xor(p3, off);
    }
    if (cg < 4) {
      int j = l & 3;
      float pv = (j == 0) ? p0 : (j == 1) ? p1 : (j == 2) ? p2 : p3;
      score_sh[rbase + kg * 4 + j] = pv;
    }
  }
  __syncthreads();  // publish scores (the only block-wide barrier)

  // ---- per-wave flash pieces over this wave's 32-row window ----
  float sc[8]; int bt[8];
#pragma unroll
  for (int i = 0; i < 8; ++i) {
    int rl = w * 32 + (i >> 2) * 16 + kg * 4 + (i & 3);
    sc[i] = score_sh[rl];
    bt[i] = batch_sh[rl];
  }
  float myscore = (l < 32) ? score_sh[w * 32 + l] : -3.0e38f;
  int   myb     = (l < 32) ? batch_sh[w * 32 + l] : -1;
  int bfirst = batch_sh[w * 32], blast = batch_sh[w * 32 + 31];
  int win = blockIdx.x * 4 + w;
  int slot = win & (PIECES - 1);

  for (int b = bfirst; b <= blast; ++b) {
    // piece max over window rows of segment b
    float x = (myb == b) ? myscore : -3.0e38f;
#pragma unroll
    for (int off = 32; off >= 1; off >>= 1) x = fmaxf(x, __shfl_xor(x, off));
    float m = x;
    // piece sum of e
    float e = (myb == b) ? __expf(myscore - m) : 0.f;
#pragma unroll
    for (int off = 32; off >= 1; off >>= 1) e += __shfl_xor(e, off);
    float s = e;
    // weighted k sum from registers
    float op[8] = {0.f, 0.f, 0.f, 0.f, 0.f, 0.f, 0.f, 0.f};
#pragma unroll
    for (int i = 0; i < 8; ++i) {
      float ei = (bt[i] == b) ? __expf(sc[i] - m) : 0.f;
      const f32x4* acc = (i < 4) ? acc0 : acc1;
      int j = i & 3;
#pragma unroll
      for (int ct = 0; ct < 8; ++ct) op[ct] = fmaf(ei, acc[ct][j], op[ct]);
    }
#pragma unroll
    for (int ct = 0; ct < 8; ++ct) {
      op[ct] += __shfl_xor(op[ct], 16);
      op[ct] += __shfl_xor(op[ct], 32);
    }
    float* pp = part + ((size_t)b * PIECES + slot) * REC;
    if (l < 16) {
#pragma unroll
      for (int ct = 0; ct < 8; ++ct) pp[8 + ct * 16 + l] = op[ct];
    }
    if (l == 0) { pp[0] = m; pp[1] = s; }
  }
}

// ---- kernel 2: merge pieces per segment (exact flash merge), write o ----
__global__ __launch_bounds__(128) void combine(
    const int* __restrict__ batch, const float* __restrict__ part,
    float* __restrict__ out) {
  int b = blockIdx.x, c = threadIdx.x;
  int start = lower_bound_i(batch, NRES, b);
  int end = lower_bound_i(batch, NRES, b + 1);
  if (end <= start) { out[b * H + c] = 0.f; return; }
  int c0 = start >> 5, c1 = (end - 1) >> 5;  // 32-row windows intersecting segment b
  float m = -3.0e38f;
  for (int ch = c0; ch <= c1; ++ch)
    m = fmaxf(m, part[((size_t)b * PIECES + (ch & (PIECES - 1))) * REC]);
  float denom = 0.f, v = 0.f;
  for (int ch = c0; ch <= c1; ++ch) {
    const float* pp = part + ((size_t)b * PIECES + (ch & (PIECES - 1))) * REC;
    float wgt = __expf(pp[0] - m);
    denom += pp[1] * wgt;
    v = fmaf(pp[8 + c], wgt, v);
  }
  out[b * H + c] = (denom > 0.f) ? v / denom : 0.f;
}

extern "C" void kernel_launch(void* const* d_in, const int* in_sizes, int n_in,
                              void* d_out, int out_size, void* d_ws, size_t ws_size,
                              hipStream_t stream) {
  const float* mol   = (const float*)d_in[0];
  const float* prot  = (const float*)d_in[1];
  const int*   batch = (const int*)d_in[2];
  const float* Wq    = (const float*)d_in[3];
  const float* bq    = (const float*)d_in[4];
  const float* Wk    = (const float*)d_in[5];
  const float* bk    = (const float*)d_in[6];
  const float* Wm    = (const float*)d_in[7];
  float* out = (float*)d_out;

  float* part = (float*)d_ws;  // NB*PIECES*REC floats ≈ 17.8 MB

  hipLaunchKernelGGL(flashkern, dim3(NCHUNK + QBLK), dim3(256), 0, stream,
                     prot, batch, Wk, bk, Wm, mol, Wq, bq, out, part);
  hipLaunchKernelGGL(combine, dim3(NB), dim3(128), 0, stream, batch, part, out);
}